// Round 8
// baseline (570.441 us; speedup 1.0000x reference)
//
#include <hip/hip_runtime.h>

// TrendGRU R8: C = W*h orientation on 16x16x32 MFMA -> 16 elems/wave,
// 2048 waves = 2 waves/SIMD (R7's 1 wave/SIMD left ~1200 cyc/t of exposed
// latency; a second wave absorbs it).
// A-operand = weights, 2 M-tiles (units 0-15, 16-23 + 8 zero pad rows);
// B-operand = h for 16 elements. ONE K=32 step: k[0..23]=h(bf16), k24=x_hi,
// k25=x_lo, k26=x_hi, k27=1.0, k28=1.0, k29..31=0. W hi/lo split (fp32
// recovery); r,z pre-scaled by log2(e), n by 2*log2(e); bias in k27/28;
// n-gate x-term as exact fp32 fma in epilogue. Quad3's B-slice (k24..31)
// is built in-register -> no x LDS staging. 12 MFMA_16 + 1 ds_read_b128 +
// 2 ds_write_b64 per wave-t. Wave-private LDS, no __syncthreads.
// Tile1 pad rows have all-zero A -> their accs are exactly 0 (finite,
// no NaN); excluded from FC by zero weights.

#define GRU_T 512
#define HS 40   // LDS row stride in shorts (80 B; 16B-aligned b128 reads)

typedef __attribute__((ext_vector_type(8))) short bf16x8;
typedef __attribute__((ext_vector_type(4))) float f32x4;

__device__ __forceinline__ float bf16hi_f(float v) {   // RNE-to-bf16, as float
    unsigned u = __float_as_uint(v);
    u = (u + 0x7FFFu + ((u >> 16) & 1u)) & 0xFFFF0000u;
    return __uint_as_float(u);
}
__device__ __forceinline__ unsigned bf16_rne(float v) {
    unsigned u = __float_as_uint(v);
    return (u + 0x7FFFu + ((u >> 16) & 1u)) >> 16;
}
// a pre-scaled by log2(e):  sigmoid = 1/(1+2^-a)
__device__ __forceinline__ float sigf(float a) {
    return __builtin_amdgcn_rcpf(1.0f + __builtin_amdgcn_exp2f(-a));
}
// v pre-scaled by 2*log2(e): tanh = 1 - 2/(2^v+1)
__device__ __forceinline__ float tnhf(float v) {
    return fmaf(-2.0f, __builtin_amdgcn_rcpf(1.0f + __builtin_amdgcn_exp2f(v)), 1.0f);
}
__device__ __forceinline__ f32x4 mfma16(bf16x8 a, bf16x8 b, f32x4 c) {
    return __builtin_amdgcn_mfma_f32_16x16x32_bf16(a, b, c, 0, 0, 0);
}

__global__ __launch_bounds__(64) void trend_gru_k32(
    const float* __restrict__ x,     // (B, T)
    const float* __restrict__ W_ih,  // (72,)
    const float* __restrict__ b_ih,  // (72,)
    const float* __restrict__ W_hh,  // (72, 24) rows r,z,n
    const float* __restrict__ b_hh,  // (72,)
    const float* __restrict__ fc_w,  // (2, 24)
    const float* __restrict__ fc_b,  // (2,)
    float* __restrict__ out)         // (B, 2)
{
    const int lane = threadIdx.x;
    const int n    = lane & 15;          // elem within wave / A row m
    const int quad = lane >> 4;
    const int elem0 = blockIdx.x * 16;

    __shared__ __align__(16) unsigned short Hlds[16 * HS];

    const float L2E = 1.4426950408889634f;

    // ---- A fragments (weights): A[m=lane&15][k=quad*8+j], per gate/tile ----
    bf16x8 Ah[3][2], Al[3][2];
#pragma unroll
    for (int g = 0; g < 3; ++g) {
        const float sc = (g == 2) ? 2.0f * L2E : L2E;
#pragma unroll
        for (int T = 0; T < 2; ++T) {
            const int u = T * 16 + n;            // unit (M row)
            const bool valid = u < 24;
            const int R = g * 24 + (valid ? u : 0);
            const float wx = (g < 2 && valid) ? sc * W_ih[R] : 0.0f;
            const float bb = valid ? sc * ((g < 2) ? (b_ih[R] + b_hh[R]) : b_hh[R]) : 0.0f;
            const float wxh = bf16hi_f(wx), bbh = bf16hi_f(bb);
            bf16x8 fh, fl;
#pragma unroll
            for (int j = 0; j < 8; ++j) {
                const int k = quad * 8 + j;
                float vh = 0.0f, vl = 0.0f;
                if (valid && k < 24) {
                    const float w  = sc * W_hh[R * 24 + k];
                    const float wh = bf16hi_f(w);
                    vh = wh; vl = w - wh;
                } else if (valid) {
                    if (k == 24 || k == 25)      vh = wxh;       // Wih_hi*(x_hi,x_lo)
                    else if (k == 26)            vh = wx - wxh;  // Wih_lo*x_hi
                    else if (k == 27)            vh = bbh;       // b_hi*1
                    else if (k == 28)            vh = bb - bbh;  // b_lo*1
                }
                fh[j] = (short)bf16_rne(vh);
                fl[j] = (short)bf16_rne(vl);
            }
            Ah[g][T] = fh;
            Al[g][T] = fl;
        }
    }

    // ---- n-gate x-path constants (exact fp32), per acc slot r ----
    // C layout (16x16): col = lane&15 = elem, row = quad*4 + r = unit.
    float wn0[4], bn0[4], wn1[4], bn1[4];
#pragma unroll
    for (int r = 0; r < 4; ++r) {
        const int u0 = quad * 4 + r;             // tile0 unit (always <16)
        const int u1 = 16 + quad * 4 + r;        // tile1 unit (valid quad<2)
        const int u1c = (u1 < 24) ? u1 : 0;
        wn0[r] = 2.0f * L2E * W_ih[48 + u0];
        bn0[r] = 2.0f * L2E * b_ih[48 + u0];
        wn1[r] = 2.0f * L2E * W_ih[48 + u1c];
        bn1[r] = 2.0f * L2E * b_ih[48 + u1c];
    }

    // ---- zero-init h region (lanes 0..15 zero their elem row, 24 shorts) ----
    if (lane < 16) {
        uint4 z4u; z4u.x = z4u.y = z4u.z = z4u.w = 0;
        uint2 z2u; z2u.x = z2u.y = 0;
        *(uint4*)(&Hlds[lane * HS])      = z4u;   // shorts 0..7
        *(uint2*)(&Hlds[lane * HS + 8])  = z2u;   // shorts 8..11
        *(uint2*)(&Hlds[lane * HS + 12]) = z2u;   // shorts 12..15
        *(uint4*)(&Hlds[lane * HS + 16]) = z4u;   // shorts 16..23
    }

    const float* xp = x + (size_t)(elem0 + n) * GRU_T;
    float xv = xp[0];

    float h0[4] = {0.f, 0.f, 0.f, 0.f};   // tile0: unit quad*4+r, elem n
    float h1[4] = {0.f, 0.f, 0.f, 0.f};   // tile1: unit 16+quad*4+r (quad<2)

#pragma unroll 1
    for (int t = 0; t < GRU_T; ++t) {
        // B fragment: col = elem = n, k = quad*8+j. quads 0..2 read h from
        // LDS; quad3's slice (k24..31) is the in-register x pack.
        uint4 bv = *(const uint4*)(&Hlds[n * HS + quad * 8]);
        {
            const unsigned uhi = bf16_rne(xv);
            const float xh = __uint_as_float(uhi << 16);
            const unsigned ulo = bf16_rne(xv - xh);
            uint4 xq;
            xq.x = uhi | (ulo << 16);        // k24=x_hi, k25=x_lo
            xq.y = uhi | 0x3F800000u;        // k26=x_hi, k27=1.0
            xq.z = 0x00003F80u;              // k28=1.0,  k29=0
            xq.w = 0;                        // k30,k31
            if (quad == 3) bv = xq;
        }
        const bf16x8 B = *(const bf16x8*)&bv;
        const float xnext = xp[(t + 1 < GRU_T) ? t + 1 : t];

        const f32x4 z4 = {0.f, 0.f, 0.f, 0.f};
        f32x4 aR0 = mfma16(Ah[0][0], B, z4); aR0 = mfma16(Al[0][0], B, aR0);
        f32x4 aR1 = mfma16(Ah[0][1], B, z4); aR1 = mfma16(Al[0][1], B, aR1);
        f32x4 aZ0 = mfma16(Ah[1][0], B, z4); aZ0 = mfma16(Al[1][0], B, aZ0);
        f32x4 aZ1 = mfma16(Ah[1][1], B, z4); aZ1 = mfma16(Al[1][1], B, aZ1);
        f32x4 aN0 = mfma16(Ah[2][0], B, z4); aN0 = mfma16(Al[2][0], B, aN0);
        f32x4 aN1 = mfma16(Ah[2][1], B, z4); aN1 = mfma16(Al[2][1], B, aN1);

        // epilogue: tile0 (all valid) + tile1 (quads 0,1 valid; others are
        // exact zeros from the zero A pad -> finite, writes predicated)
        unsigned p0[4], p1[4];
#pragma unroll
        for (int r = 0; r < 4; ++r) {
            {
                const float rr = sigf(aR0[r]);
                const float zz = sigf(aZ0[r]);
                const float ax = fmaf(wn0[r], xv, bn0[r]);
                const float nn = tnhf(fmaf(rr, aN0[r], ax));
                const float hn = fmaf(zz, h0[r] - nn, nn);
                h0[r] = hn;
                unsigned u = __float_as_uint(hn);
                p0[r] = u + 0x7FFFu + ((u >> 16) & 1u);
            }
            {
                const float rr = sigf(aR1[r]);
                const float zz = sigf(aZ1[r]);
                const float ax = fmaf(wn1[r], xv, bn1[r]);
                const float nn = tnhf(fmaf(rr, aN1[r], ax));
                const float hn = fmaf(zz, h1[r] - nn, nn);
                h1[r] = hn;
                unsigned u = __float_as_uint(hn);
                p1[r] = u + 0x7FFFu + ((u >> 16) & 1u);
            }
        }
        // pack: perm(a=HIGH,b=LOW): 0x07060302 -> [bf16(s0) | bf16(s1)<<16]
        {
            uint2 d;
            d.x = __builtin_amdgcn_perm(p0[1], p0[0], 0x07060302u);
            d.y = __builtin_amdgcn_perm(p0[3], p0[2], 0x07060302u);
            *(uint2*)(&Hlds[n * HS + quad * 4]) = d;          // units 4q..4q+3
        }
        if (quad < 2) {
            uint2 d;
            d.x = __builtin_amdgcn_perm(p1[1], p1[0], 0x07060302u);
            d.y = __builtin_amdgcn_perm(p1[3], p1[2], 0x07060302u);
            *(uint2*)(&Hlds[n * HS + 16 + quad * 4]) = d;     // units 16+4q..
        }
        xv = xnext;
    }

    // ---- FC head (weights loaded only now -> keeps loop VGPRs low) ----
    float o0 = 0.0f, o1 = 0.0f;
#pragma unroll
    for (int r = 0; r < 4; ++r) {
        const int u0 = quad * 4 + r;
        o0 = fmaf(h0[r], fc_w[u0],      o0);
        o1 = fmaf(h0[r], fc_w[24 + u0], o1);
    }
    if (quad < 2) {
#pragma unroll
        for (int r = 0; r < 4; ++r) {
            const int u1 = 16 + quad * 4 + r;
            o0 = fmaf(h1[r], fc_w[u1],      o0);
            o1 = fmaf(h1[r], fc_w[24 + u1], o1);
        }
    }
    o0 += __shfl_xor(o0, 16);  o1 += __shfl_xor(o1, 16);
    o0 += __shfl_xor(o0, 32);  o1 += __shfl_xor(o1, 32);
    if (lane < 16) {
        float2 o; o.x = o0 + fc_b[0]; o.y = o1 + fc_b[1];
        *(float2*)(out + (size_t)(elem0 + n) * 2) = o;
    }
}

extern "C" void kernel_launch(void* const* d_in, const int* in_sizes, int n_in,
                              void* d_out, int out_size, void* d_ws, size_t ws_size,
                              hipStream_t stream) {
    const float* x    = (const float*)d_in[0];
    const float* W_ih = (const float*)d_in[1];
    const float* b_ih = (const float*)d_in[2];
    const float* W_hh = (const float*)d_in[3];
    const float* b_hh = (const float*)d_in[4];
    const float* fc_w = (const float*)d_in[5];
    const float* fc_b = (const float*)d_in[6];
    float* out = (float*)d_out;

    const int B = in_sizes[0] / GRU_T;      // 32768
    const int grid = B / 16;                // 2048 blocks x 1 wave -> 2/SIMD
    trend_gru_k32<<<grid, 64, 0, stream>>>(x, W_ih, b_ih, W_hh, b_hh,
                                           fc_w, fc_b, out);
}

// Round 9
// 495.317 us; speedup vs baseline: 1.1517x; 1.1517x over previous
//
#include <hip/hip_runtime.h>

// TrendGRU R9: R7 (32x32x16, C = W*h, zero-waste epilogue) with the LDS
// h round-trip replaced by an in-register cross-half exchange.
// In this orientation C-layout and B-layout both keep element = lane&31;
// only the unit axis moves across the half-wave boundary. So:
//   pack h (12 units/lane) into 6 bf16x2 dwords -> __shfl_xor(.,32) -> 8
//   cndmask selects build the next step's B0/B1 fragments. No LDS, no
//   lgkm round-trip latency, no bank conflicts in the loop.
// Index algebra (half = lane>>5, G = reg>>2):
//   own dwords P[G][i] hold units (8G+4*half) + {2i, 2i+1}
//   B0 (k=unit 0..15):  half0 = {P0,P0',Q0,Q0'}, half1 = {Q1,Q1',P1,P1'}
//   B1 (k16..23=units 16..23, k24..31=x-pack):
//                       half0 = {P2,P2',Q2,Q2'}, half1 = x-pack
// W hi/lo split (fp32 recovery); r,z pre-scaled by log2(e), n by 2*log2(e);
// bias in k27/28; n-gate x-term as exact fp32 fma. 12 MFMA_32 per wave-t.

#define GRU_T 512
#define FS 28   // FC LDS row stride in floats (head only, outside the loop)

typedef __attribute__((ext_vector_type(8)))  short bf16x8;
typedef __attribute__((ext_vector_type(16))) float f32x16;

__device__ __forceinline__ float bf16hi_f(float v) {   // RNE-to-bf16, as float
    unsigned u = __float_as_uint(v);
    u = (u + 0x7FFFu + ((u >> 16) & 1u)) & 0xFFFF0000u;
    return __uint_as_float(u);
}
__device__ __forceinline__ unsigned bf16_rne(float v) {
    unsigned u = __float_as_uint(v);
    return (u + 0x7FFFu + ((u >> 16) & 1u)) >> 16;
}
// a pre-scaled by log2(e):  sigmoid = 1/(1+2^-a)
__device__ __forceinline__ float sigf(float a) {
    return __builtin_amdgcn_rcpf(1.0f + __builtin_amdgcn_exp2f(-a));
}
// v pre-scaled by 2*log2(e): tanh = 1 - 2/(2^v+1)
__device__ __forceinline__ float tnhf(float v) {
    return fmaf(-2.0f, __builtin_amdgcn_rcpf(1.0f + __builtin_amdgcn_exp2f(v)), 1.0f);
}
__device__ __forceinline__ f32x16 mfma32(bf16x8 a, bf16x8 b, f32x16 c) {
    return __builtin_amdgcn_mfma_f32_32x32x16_bf16(a, b, c, 0, 0, 0);
}

__global__ __launch_bounds__(64) void trend_gru_r9(
    const float* __restrict__ x,     // (B, T)
    const float* __restrict__ W_ih,  // (72,)
    const float* __restrict__ b_ih,  // (72,)
    const float* __restrict__ W_hh,  // (72, 24) rows r,z,n
    const float* __restrict__ b_hh,  // (72,)
    const float* __restrict__ fc_w,  // (2, 24)
    const float* __restrict__ fc_b,  // (2,)
    float* __restrict__ out)         // (B, 2)
{
    const int lane = threadIdx.x;
    const int e    = lane & 31;          // element (B/C column)
    const int half = lane >> 5;
    const int elem0 = blockIdx.x * 32;

    __shared__ __align__(16) float Flds[32 * FS];   // FC head only

    const float L2E = 1.4426950408889634f;

    // ---- A fragments (weights), built once: A[gate][kstep][hi/lo] ----
    // A layout: row m = lane&31 (= gate unit), k = kstep*16 + half*8 + jj.
    bf16x8 A[3][2][2];
#pragma unroll
    for (int g = 0; g < 3; ++g) {
        const float sc = (g == 2) ? 2.0f * L2E : L2E;
        const int m = e;
        const bool valid = m < 24;
        const int R = g * 24 + (valid ? m : 0);
        const float wx = (g < 2 && valid) ? sc * W_ih[R] : 0.0f;
        const float bb = valid ? sc * ((g < 2) ? (b_ih[R] + b_hh[R]) : b_hh[R]) : 0.0f;
        const float wxh = bf16hi_f(wx), bbh = bf16hi_f(bb);
#pragma unroll
        for (int s = 0; s < 2; ++s) {
            bf16x8 fh, fl;
#pragma unroll
            for (int jj = 0; jj < 8; ++jj) {
                const int k = s * 16 + half * 8 + jj;
                float vh = 0.0f, vl = 0.0f;
                if (valid && k < 24) {
                    const float w  = sc * W_hh[R * 24 + k];
                    const float wh = bf16hi_f(w);
                    vh = wh; vl = w - wh;
                } else if (valid) {
                    if (k == 24 || k == 25)      vh = wxh;       // Wih_hi*(x_hi,x_lo)
                    else if (k == 26)            vh = wx - wxh;  // Wih_lo*x_hi
                    else if (k == 27)            vh = bbh;       // b_hi*1
                    else if (k == 28)            vh = bb - bbh;  // b_lo*1
                }
                fh[jj] = (short)bf16_rne(vh);
                fl[jj] = (short)bf16_rne(vl);
            }
            A[g][s][0] = fh;
            A[g][s][1] = fl;
        }
    }

    // ---- per-lane n-gate x-path constants (exact fp32) ----
    // C-layout slot s (0..11) -> unit j = (s&3) + 8*(s>>2) + 4*half
    float wn_s[12], bn_s[12];
#pragma unroll
    for (int s = 0; s < 12; ++s) {
        const int j = (s & 3) + 8 * (s >> 2) + 4 * half;
        wn_s[s] = 2.0f * L2E * W_ih[48 + j];
        bn_s[s] = 2.0f * L2E * b_ih[48 + j];
    }

    const float* xp = x + (size_t)(elem0 + e) * GRU_T;
    float xv = xp[0];

    float h[12];
#pragma unroll
    for (int s = 0; s < 12; ++s) h[s] = 0.0f;

    // packed h dwords: P[G][i] = units (8G + 4*half) + {2i, 2i+1}
    unsigned P[3][2];
#pragma unroll
    for (int G = 0; G < 3; ++G) { P[G][0] = 0u; P[G][1] = 0u; }

    const f32x16 z16 = {0.f,0.f,0.f,0.f,0.f,0.f,0.f,0.f,
                        0.f,0.f,0.f,0.f,0.f,0.f,0.f,0.f};

#pragma unroll 1
    for (int t = 0; t < GRU_T; ++t) {
        // x-pack for B1/half1 (k24=x_hi, k25=x_lo, k26=x_hi, k27=1, k28=1)
        uint4 xq;
        {
            const unsigned uhi = bf16_rne(xv);
            const float xh = __uint_as_float(uhi << 16);
            const unsigned ulo = bf16_rne(xv - xh);
            xq.x = uhi | (ulo << 16);
            xq.y = uhi | 0x3F800000u;
            xq.z = 0x00003F80u;
            xq.w = 0u;
        }

        // cross-half exchange: Q[G][i] = partner's P[G][i]
        unsigned Q[3][2];
#pragma unroll
        for (int G = 0; G < 3; ++G) {
            Q[G][0] = __shfl_xor((int)P[G][0], 32);
            Q[G][1] = __shfl_xor((int)P[G][1], 32);
        }

        // assemble B fragments (element column stays in-lane)
        uint4 b0v, b1v;
        b0v.x = half ? Q[1][0] : P[0][0];
        b0v.y = half ? Q[1][1] : P[0][1];
        b0v.z = half ? P[1][0] : Q[0][0];
        b0v.w = half ? P[1][1] : Q[0][1];
        b1v.x = half ? xq.x : P[2][0];
        b1v.y = half ? xq.y : P[2][1];
        b1v.z = half ? xq.z : Q[2][0];
        b1v.w = half ? xq.w : Q[2][1];
        const bf16x8 B0 = *(const bf16x8*)&b0v;
        const bf16x8 B1 = *(const bf16x8*)&b1v;

        const float xnext = xp[(t + 1 < GRU_T) ? t + 1 : t];

        f32x16 aR = mfma32(A[0][0][0], B0, z16);
        aR = mfma32(A[0][0][1], B0, aR);
        aR = mfma32(A[0][1][0], B1, aR);
        aR = mfma32(A[0][1][1], B1, aR);
        f32x16 aZ = mfma32(A[1][0][0], B0, z16);
        aZ = mfma32(A[1][0][1], B0, aZ);
        aZ = mfma32(A[1][1][0], B1, aZ);
        aZ = mfma32(A[1][1][1], B1, aZ);
        f32x16 aN = mfma32(A[2][0][0], B0, z16);
        aN = mfma32(A[2][0][1], B0, aN);
        aN = mfma32(A[2][1][0], B1, aN);
        aN = mfma32(A[2][1][1], B1, aN);

        // epilogue: acc regs 0..11 (12..15 = pad units 24..31, skipped)
#pragma unroll
        for (int G = 0; G < 3; ++G) {
            unsigned u4[4];
#pragma unroll
            for (int q = 0; q < 4; ++q) {
                const int s = G * 4 + q;
                const float rr  = sigf(aR[s]);
                const float zz  = sigf(aZ[s]);
                const float aXv = fmaf(wn_s[s], xv, bn_s[s]);
                const float nn  = tnhf(fmaf(rr, aN[s], aXv));
                const float hn  = fmaf(zz, h[s] - nn, nn);
                h[s] = hn;
                unsigned u = __float_as_uint(hn);
                u4[q] = u + 0x7FFFu + ((u >> 16) & 1u);
            }
            // perm(a=HIGH,b=LOW): 0x07060302 -> [bf16(q0) | bf16(q1)<<16]
            P[G][0] = __builtin_amdgcn_perm(u4[1], u4[0], 0x07060302u);
            P[G][1] = __builtin_amdgcn_perm(u4[3], u4[2], 0x07060302u);
        }
        xv = xnext;
    }

    // ---- FC head: h (fp32) -> LDS, lanes 0..31 reduce 24 -> 2 ----
#pragma unroll
    for (int G = 0; G < 3; ++G) {
        float4 f4;
        f4.x = h[G * 4 + 0]; f4.y = h[G * 4 + 1];
        f4.z = h[G * 4 + 2]; f4.w = h[G * 4 + 3];
        *(float4*)(&Flds[e * FS + G * 8 + half * 4]) = f4;
    }
    __builtin_amdgcn_s_waitcnt(0);   // lgkmcnt(0): same-wave LDS visibility
    if (lane < 32) {
        float o0 = fc_b[0], o1 = fc_b[1];
#pragma unroll
        for (int j = 0; j < 24; ++j) {
            const float hv = Flds[lane * FS + j];
            o0 = fmaf(hv, fc_w[j],      o0);
            o1 = fmaf(hv, fc_w[24 + j], o1);
        }
        float2 o; o.x = o0; o.y = o1;
        *(float2*)(out + (size_t)(elem0 + lane) * 2) = o;
    }
}

extern "C" void kernel_launch(void* const* d_in, const int* in_sizes, int n_in,
                              void* d_out, int out_size, void* d_ws, size_t ws_size,
                              hipStream_t stream) {
    const float* x    = (const float*)d_in[0];
    const float* W_ih = (const float*)d_in[1];
    const float* b_ih = (const float*)d_in[2];
    const float* W_hh = (const float*)d_in[3];
    const float* b_hh = (const float*)d_in[4];
    const float* fc_w = (const float*)d_in[5];
    const float* fc_b = (const float*)d_in[6];
    float* out = (float*)d_out;

    const int B = in_sizes[0] / GRU_T;      // 32768
    const int grid = B / 32;                // 1024 blocks x 1 wave
    trend_gru_r9<<<grid, 64, 0, stream>>>(x, W_ih, b_ih, W_hh, b_hh,
                                          fc_w, fc_b, out);
}